// Round 8
// baseline (947.257 us; speedup 1.0000x reference)
//
#include <hip/hip_runtime.h>
#include <stdint.h>

typedef __attribute__((ext_vector_type(8))) short short8;
typedef __attribute__((ext_vector_type(4))) float floatx4;
typedef __attribute__((ext_vector_type(2))) uint uint2v;

#define INV_SQRT2F 0.70710678118654752440f

// fragment-ordered bf16 weights (8.5 MB), filled by k_cvt each call
__device__ ushort g_wbuf[4259840];

__device__ __forceinline__ ushort f2bf(float f) {
    union { float f; uint32_t u; } c; c.f = f;
    uint32_t x = c.u;
    return (ushort)((x + 0x7fffu + ((x >> 16) & 1u)) >> 16);  // RTNE
}
__device__ __forceinline__ float softplus100(float x) {
    float z = 100.f * x;
    return fmaxf(x, 0.f) + __logf(1.f + __expf(-fabsf(z))) * 0.01f;
}
__device__ __forceinline__ int swz(int row, int col) {
    return (((col >> 3) ^ (row & 7)) << 3) | (col & 7);
}
// LDS-only barrier: waits lgkmcnt(0) but NOT vmcnt -> global prefetch loads
// stay in flight across the barrier.
__device__ __forceinline__ void sync_lds() {
    asm volatile("s_waitcnt lgkmcnt(0)" ::: "memory");
    __builtin_amdgcn_s_barrier();
    asm volatile("" ::: "memory");
}

// ---------------- weight cvt + fragment reorder ----------------
// dest per cluster: short8 i8 = (t*K32 + kc)*64 + lane; elem j:
// n = t*16 + (lane&15), k = kc*32 + (lane>>4)*8 + j. Zeros at edges.
struct Seg { const float* s; int off, nout, kw, k32, ttot, nclust; };
struct CvtAll { Seg seg[16]; };

__global__ void k_cvt(CvtAll c) {
    Seg sg = c.seg[blockIdx.y];
    ushort* d = g_wbuf + sg.off;
    const int pcs8 = sg.ttot * sg.k32 * 64;
    const int tot8 = pcs8 * sg.nclust;
    for (int i8 = blockIdx.x * blockDim.x + threadIdx.x; i8 < tot8;
         i8 += gridDim.x * blockDim.x) {
        int cl = i8 / pcs8;
        int r = i8 - cl * pcs8;
        int t = r / (sg.k32 * 64);
        int r2 = r - t * (sg.k32 * 64);
        int kc = r2 >> 6;
        int lane = r2 & 63;
        int n = t * 16 + (lane & 15);
        int kb = kc * 32 + (lane >> 4) * 8;
        const float* src = sg.s + (size_t)cl * sg.nout * sg.kw;
        short8 v = {0, 0, 0, 0, 0, 0, 0, 0};
        if (n < sg.nout) {
#pragma unroll
            for (int j = 0; j < 8; ++j) {
                int k = kb + j;
                if (k < sg.kw) v[j] = (short)f2bf(src[n * sg.kw + k]);
            }
        }
        *(short8*)(d + (size_t)i8 * 8) = v;
    }
}

// ---------------- embedding: 64 rows, cols 0..63 (zeros beyond 38) ----------------
template<int STRIDE>
__device__ void embed64(short* act, const float* pts, int row0, short* inp_sv) {
    for (int idx = threadIdx.x; idx < 64 * 64; idx += 512) {
        int row = idx >> 6, col = idx & 63;
        float v = 0.f;
        if (col < 39) {
            int comp = (col < 3) ? col : (col - 3) % 3;
            float x = pts[(row0 + row) * 3 + comp];
            if (col < 3) v = x;
            else {
                int b = col - 3; int fi = b / 6; int r = b % 6;
                float a = x * (float)(1 << fi);
                v = (r < 3) ? __sinf(a) : __cosf(a);
            }
        }
        act[row * STRIDE + swz(row, col)] = (short)f2bf(v);
        if (inp_sv && col < 39) inp_sv[row * 40 + col] = (short)f2bf(v * INV_SQRT2F);
    }
}

// ---------------- big layer: 64 rows, 8 waves, i=4 t-tiles x j=4 m-tiles ----------------
// Swapped operands: mfma(W, act) -> D rows = out-channel n, cols = act row.
// Weights read once per block. w0/w1 preloaded (kc=0,1); final iterations
// issue the NEXT layer's kc=0,1 into them (fly across sync_lds barriers).
template<int ACT, int STRIDE, int K32>
__device__ __forceinline__ void big_layer(
    short* act, const ushort* __restrict__ Wf, const float* __restrict__ bias,
    int Nout, float scale, bool toLds, float* gOut, int gCol0, int gRow0,
    short8 (&w0)[4], short8 (&w1)[4],
    const ushort* nextW, int nStrideT, int nTtot)
{
    const int tid = threadIdx.x;
    const int wave = tid >> 6, lane = tid & 63;
    const int q = lane >> 4, li = lane & 15;
    const int Ttot = (Nout + 15) >> 4;

    floatx4 acc[4][4];   // [i = t-sub][j = m-sub]
#pragma unroll
    for (int i = 0; i < 4; ++i)
#pragma unroll
        for (int j = 0; j < 4; ++j) acc[i][j] = (floatx4){0.f, 0.f, 0.f, 0.f};

    bool tv[4]; const ushort* wb[4];
#pragma unroll
    for (int i = 0; i < 4; ++i) {
        int t = wave + 8 * i;
        tv[i] = t < Ttot;
        wb[i] = Wf + (size_t)t * (K32 * 512) + lane * 8;
    }
    int rowoff[4], r7[4];
#pragma unroll
    for (int j = 0; j < 4; ++j) {
        int row = j * 16 + li;
        rowoff[j] = row * STRIDE;
        r7[j] = row & 7;
    }

    auto loadW = [&](int kc, short8 (&w)[4]) {
#pragma unroll
        for (int i = 0; i < 4; ++i)
            if (tv[i]) w[i] = *(const short8*)(wb[i] + kc * 512);
    };
    auto loadNext = [&](int kc, short8 (&w)[4]) {
        if (!nextW) return;
#pragma unroll
        for (int i = 0; i < 4; ++i) {
            int t = wave + 8 * i;
            if (t < nTtot)
                w[i] = *(const short8*)(nextW + (size_t)t * nStrideT + kc * 512 + lane * 8);
        }
    };
    auto step = [&](int kc, short8 (&w)[4]) {
        const int gq = kc * 4 + q;
        short8 afr[4];
#pragma unroll
        for (int j = 0; j < 4; ++j)
            afr[j] = *(const short8*)&act[rowoff[j] + ((gq ^ r7[j]) << 3)];
#pragma unroll
        for (int i = 0; i < 4; ++i) {
            if (!tv[i]) continue;
#pragma unroll
            for (int j = 0; j < 4; ++j)
                acc[i][j] = __builtin_amdgcn_mfma_f32_16x16x32_bf16(w[i], afr[j], acc[i][j], 0, 0, 0);
        }
    };

#pragma unroll
    for (int kc = 0; kc < K32; kc += 2) {
        step(kc, w0);
        if (kc + 2 < K32) loadW(kc + 2, w0); else loadNext(0, w0);
        step(kc + 1, w1);
        if (kc + 3 < K32) loadW(kc + 3, w1); else loadNext(1, w1);
    }
    sync_lds();  // all act reads done before epilogue overwrites
#pragma unroll
    for (int i = 0; i < 4; ++i) {
        if (!tv[i]) continue;
        const int nb = (wave + 8 * i) * 16 + q * 4;
        if (nb >= Nout) continue;
        const bool fullN = (nb + 4) <= Nout;
        float bs[4];
        if (fullN) {
            float4 b4 = *(const float4*)(bias + nb);
            bs[0] = b4.x; bs[1] = b4.y; bs[2] = b4.z; bs[3] = b4.w;
        } else {
#pragma unroll
            for (int r = 0; r < 4; ++r) bs[r] = (nb + r < Nout) ? bias[nb + r] : 0.f;
        }
#pragma unroll
        for (int j = 0; j < 4; ++j) {
            const int row = j * 16 + li;
            float v[4];
#pragma unroll
            for (int r = 0; r < 4; ++r) {
                float x = acc[i][j][r] + bs[r];
                if (ACT == 1) x = softplus100(x);
                else if (ACT == 2) x = fmaxf(x, 0.f);
                else if (ACT == 3) x = tanhf(x);
                v[r] = x * scale;
            }
            if (toLds) {
                if (fullN) {
                    uint lo = (uint)f2bf(v[0]) | ((uint)f2bf(v[1]) << 16);
                    uint hi = (uint)f2bf(v[2]) | ((uint)f2bf(v[3]) << 16);
                    int g = (nb >> 3) ^ (row & 7);
                    uint2v pk = {lo, hi};
                    *(uint2v*)&act[row * STRIDE + (g << 3) + (nb & 7)] = pk;
                } else {
#pragma unroll
                    for (int r = 0; r < 4; ++r)
                        if (nb + r < Nout)
                            act[row * STRIDE + swz(row, nb + r)] = (short)f2bf(v[r]);
                }
            } else {
#pragma unroll
                for (int r = 0; r < 4; ++r)
                    if (nb + r < Nout)
                        gOut[(size_t)(gRow0 + row) * 263 + gCol0 + nb + r] = v[r];
            }
        }
    }
}

// ---------------- small layer (mult net): 64 rows, i=1 t x j=4 m ----------------
template<int ACT, int K32>
__device__ __forceinline__ void small_layer(
    short* act, const ushort* __restrict__ Wf, const float* __restrict__ bias,
    int Nout, bool toLds, float* gOut, int gCol0, int gRow0,
    short8& w0, short8& w1, const ushort* nextW, int nStrideT, int nTtot)
{
    const int tid = threadIdx.x;
    const int wave = tid >> 6, lane = tid & 63;
    const int q = lane >> 4, li = lane & 15;
    const int Ttot = (Nout + 15) >> 4;
    const int t = wave;
    const bool tv = t < Ttot;
    const ushort* wb = Wf + (size_t)t * (K32 * 512) + lane * 8;

    floatx4 acc[4];
#pragma unroll
    for (int j = 0; j < 4; ++j) acc[j] = (floatx4){0.f, 0.f, 0.f, 0.f};

    auto loadW = [&](int kc, short8& w) {
        if (tv) w = *(const short8*)(wb + kc * 512);
    };
    auto loadNext = [&](int kc, short8& w) {
        if (nextW && t < nTtot)
            w = *(const short8*)(nextW + (size_t)t * nStrideT + kc * 512 + lane * 8);
    };
    auto step = [&](int kc, short8& w) {
        const int gq = kc * 4 + q;
        short8 afr[4];
#pragma unroll
        for (int j = 0; j < 4; ++j) {
            int row = j * 16 + li;
            afr[j] = *(const short8*)&act[row * 128 + ((gq ^ (row & 7)) << 3)];
        }
        if (tv)
#pragma unroll
            for (int j = 0; j < 4; ++j)
                acc[j] = __builtin_amdgcn_mfma_f32_16x16x32_bf16(w, afr[j], acc[j], 0, 0, 0);
    };
#pragma unroll
    for (int kc = 0; kc < K32; kc += 2) {
        step(kc, w0);
        if (kc + 2 < K32) loadW(kc + 2, w0); else loadNext(0, w0);
        step(kc + 1, w1);
        if (kc + 3 < K32) loadW(kc + 3, w1); else loadNext(1, w1);
    }
    sync_lds();
    if (tv) {
        const int nb = t * 16 + q * 4;
        if (nb < Nout) {
            const bool fullN = (nb + 4) <= Nout;
            float bs[4];
#pragma unroll
            for (int r = 0; r < 4; ++r) bs[r] = (nb + r < Nout) ? bias[nb + r] : 0.f;
#pragma unroll
            for (int j = 0; j < 4; ++j) {
                const int row = j * 16 + li;
                float v[4];
#pragma unroll
                for (int r = 0; r < 4; ++r) {
                    float x = acc[j][r] + bs[r];
                    if (ACT == 2) x = fmaxf(x, 0.f);
                    else if (ACT == 3) x = tanhf(x);
                    v[r] = x;
                }
                if (toLds) {
                    if (fullN) {
                        uint lo = (uint)f2bf(v[0]) | ((uint)f2bf(v[1]) << 16);
                        uint hi = (uint)f2bf(v[2]) | ((uint)f2bf(v[3]) << 16);
                        int g = (nb >> 3) ^ (row & 7);
                        uint2v pk = {lo, hi};
                        *(uint2v*)&act[row * 128 + (g << 3) + (nb & 7)] = pk;
                    } else {
#pragma unroll
                        for (int r = 0; r < 4; ++r)
                            if (nb + r < Nout)
                                act[row * 128 + swz(row, nb + r)] = (short)f2bf(v[r]);
                    }
                } else {
#pragma unroll
                    for (int r = 0; r < 4; ++r)
                        if (nb + r < Nout)
                            gOut[(size_t)(gRow0 + row) * 263 + gCol0 + nb + r] = v[r];
                }
            }
        }
    }
}

// ---------------- implicit network: 512 blocks x 512 thr, 2 blocks/CU ----------------
struct IP { int iw[9]; const float* ib[9]; };

__global__ __launch_bounds__(512, 4) void k_impl(const float* __restrict__ pts,
                                                 IP p, float* __restrict__ out) {
    __shared__ __align__(16) short act[64 * 512];
    __shared__ short inp_sv[64 * 40];
    const int row0 = blockIdx.x * 64;
    const int wave = threadIdx.x >> 6, lane = threadIdx.x & 63;

    short8 w0[4], w1[4];
    // prefetch layer-0 weights (K32=2) before the embed's sin/cos burst
#pragma unroll
    for (int i = 0; i < 4; ++i) {
        const ushort* b = g_wbuf + p.iw[0] + ((wave + 8 * i) * (2 * 512)) + lane * 8;
        w0[i] = *(const short8*)b;
        w1[i] = *(const short8*)(b + 512);
    }
    embed64<512>(act, pts, row0, inp_sv);
    sync_lds();
    big_layer<1, 512, 2>(act, g_wbuf + p.iw[0], p.ib[0], 512, 1.f, true, nullptr, 0, 0,
                         w0, w1, g_wbuf + p.iw[1], 8192, 32);
    sync_lds();
    big_layer<1, 512, 16>(act, g_wbuf + p.iw[1], p.ib[1], 512, 1.f, true, nullptr, 0, 0,
                          w0, w1, g_wbuf + p.iw[2], 8192, 32);
    sync_lds();
    big_layer<1, 512, 16>(act, g_wbuf + p.iw[2], p.ib[2], 512, 1.f, true, nullptr, 0, 0,
                          w0, w1, g_wbuf + p.iw[3], 8192, 32);
    sync_lds();
    // layer 3: softplus then pre-scale by 1/sqrt(2) (skip-concat scale)
    big_layer<1, 512, 16>(act, g_wbuf + p.iw[3], p.ib[3], 473, INV_SQRT2F, true, nullptr, 0, 0,
                          w0, w1, g_wbuf + p.iw[4], 8192, 32);
    // append inp * 1/sqrt(2) into cols 473..511 (disjoint from epilogue writes)
    for (int idx = threadIdx.x; idx < 64 * 64; idx += 512) {
        int row = idx >> 6, col = idx & 63;
        if (col < 39) act[row * 512 + swz(row, 473 + col)] = inp_sv[row * 40 + col];
    }
    sync_lds();
    big_layer<1, 512, 16>(act, g_wbuf + p.iw[4], p.ib[4], 512, 1.f, true, nullptr, 0, 0,
                          w0, w1, g_wbuf + p.iw[5], 8192, 32);
    sync_lds();
    big_layer<1, 512, 16>(act, g_wbuf + p.iw[5], p.ib[5], 512, 1.f, true, nullptr, 0, 0,
                          w0, w1, g_wbuf + p.iw[6], 8192, 32);
    sync_lds();
    big_layer<1, 512, 16>(act, g_wbuf + p.iw[6], p.ib[6], 512, 1.f, true, nullptr, 0, 0,
                          w0, w1, g_wbuf + p.iw[7], 8192, 32);
    sync_lds();
    big_layer<1, 512, 16>(act, g_wbuf + p.iw[7], p.ib[7], 512, 1.f, true, nullptr, 0, 0,
                          w0, w1, g_wbuf + p.iw[8], 8192, 17);
    sync_lds();
    big_layer<0, 512, 16>(act, g_wbuf + p.iw[8], p.ib[8], 257, 1.f, false, out, 0, row0,
                          w0, w1, nullptr, 0, 0);
}

// ---------------- displacement + multi networks ----------------
struct DMP { int dw[4]; const float* db[4]; int mw[3]; const float* mb[3]; };

__global__ __launch_bounds__(512, 4) void k_dm(const float* __restrict__ pts,
                                               DMP p, float* __restrict__ out,
                                               int nbD, int rpc) {
    __shared__ __align__(16) short act[64 * 512];
    const int bid = blockIdx.x;
    const int wave = threadIdx.x >> 6, lane = threadIdx.x & 63;
    if (bid < nbD) {
        const int row0 = bid * 64;
        short8 w0[4], w1[4];
#pragma unroll
        for (int i = 0; i < 4; ++i) {
            const ushort* b = g_wbuf + p.dw[0] + ((wave + 8 * i) * (2 * 512)) + lane * 8;
            w0[i] = *(const short8*)b;
            w1[i] = *(const short8*)(b + 512);
        }
        embed64<512>(act, pts, row0, nullptr);
        sync_lds();
        big_layer<2, 512, 2>(act, g_wbuf + p.dw[0], p.db[0], 512, 1.f, true, nullptr, 0, 0,
                             w0, w1, g_wbuf + p.dw[1], 8192, 32);
        sync_lds();
        big_layer<2, 512, 16>(act, g_wbuf + p.dw[1], p.db[1], 512, 1.f, true, nullptr, 0, 0,
                              w0, w1, g_wbuf + p.dw[2], 8192, 32);
        sync_lds();
        big_layer<2, 512, 16>(act, g_wbuf + p.dw[2], p.db[2], 512, 1.f, true, nullptr, 0, 0,
                              w0, w1, g_wbuf + p.dw[3], 8192, 1);
        sync_lds();
        big_layer<3, 512, 16>(act, g_wbuf + p.dw[3], p.db[3], 3, 1.f, false, out, 257, row0,
                              w0, w1, nullptr, 0, 0);
    } else {
        const int row0 = (bid - nbD) * 64;
        const int c = row0 / rpc;
        // per-cluster fragment sizes: L0 8192, L1 16384, L2 2048 shorts
        const ushort* m0 = g_wbuf + p.mw[0] + c * 8192;
        const ushort* m1 = g_wbuf + p.mw[1] + c * 16384;
        const ushort* m2 = g_wbuf + p.mw[2] + c * 2048;
        short8 w0, w1;
        {
            const ushort* b = m0 + (size_t)wave * (2 * 512) + lane * 8;
            w0 = *(const short8*)b;
            w1 = *(const short8*)(b + 512);
        }
        embed64<128>(act, pts, row0, nullptr);
        sync_lds();
        small_layer<2, 2>(act, m0, p.mb[0] + c * 128, 128, true, nullptr, 0, 0,
                          w0, w1, m1, 2048, 8);
        sync_lds();
        small_layer<2, 4>(act, m1, p.mb[1] + c * 128, 128, true, nullptr, 0, 0,
                          w0, w1, m2, 2048, 1);
        sync_lds();
        small_layer<3, 4>(act, m2, p.mb[2] + c * 3, 3, false, out, 260, row0,
                          w0, w1, nullptr, 0, 0);
    }
}

extern "C" void kernel_launch(void* const* d_in, const int* in_sizes, int n_in,
                              void* d_out, int out_size, void* d_ws, size_t ws_size,
                              hipStream_t stream) {
    const float* pts = (const float*)d_in[0];
    float* out = (float*)d_out;
    const int N = in_sizes[0] / 3;       // 32768
    const int nbI = N / 64;              // 512
    const int nbD = N / 64;              // 512
    const int nbM = N / 64;              // 512
    const int rpc = N / 64;              // rows per cluster (512)

    const int iN[9] = {512, 512, 512, 473, 512, 512, 512, 512, 257};
    const int iK[9] = {39, 512, 512, 512, 512, 512, 512, 512, 512};
    const int dN[4] = {512, 512, 512, 3};
    const int dK[4] = {39, 512, 512, 512};
    const int mN[3] = {128, 128, 3};
    const int mK[3] = {39, 128, 128};

    CvtAll cv; IP ip; DMP dm;
    int off = 0, seg = 0;
    auto add_seg = [&](const float* src, int nout, int kw, int nclust) -> int {
        int k32 = ((kw + 31) & ~31) / 32;
        int ttot = (nout + 15) >> 4;
        cv.seg[seg].s = src; cv.seg[seg].off = off;
        cv.seg[seg].nout = nout; cv.seg[seg].kw = kw;
        cv.seg[seg].k32 = k32; cv.seg[seg].ttot = ttot; cv.seg[seg].nclust = nclust;
        int my = off;
        off += ttot * k32 * 512 * nclust;
        ++seg;
        return my;
    };
    for (int l = 0; l < 9; ++l) {
        ip.iw[l] = add_seg((const float*)d_in[1 + 2 * l], iN[l], iK[l], 1);
        ip.ib[l] = (const float*)d_in[2 + 2 * l];
    }
    for (int l = 0; l < 4; ++l) {
        dm.dw[l] = add_seg((const float*)d_in[19 + 2 * l], dN[l], dK[l], 1);
        dm.db[l] = (const float*)d_in[20 + 2 * l];
    }
    for (int l = 0; l < 3; ++l) {
        dm.mw[l] = add_seg((const float*)d_in[27 + 2 * l], mN[l], mK[l], 64);
        dm.mb[l] = (const float*)d_in[28 + 2 * l];
    }

    k_cvt<<<dim3(256, 16), 256, 0, stream>>>(cv);
    k_impl<<<nbI, 512, 0, stream>>>(pts, ip, out);
    k_dm<<<nbD + nbM, 512, 0, stream>>>(pts, dm, out, nbD, rpc);
}

// Round 9
// 464.813 us; speedup vs baseline: 2.0379x; 2.0379x over previous
//
#include <hip/hip_runtime.h>
#include <stdint.h>

typedef __attribute__((ext_vector_type(8))) short short8;
typedef __attribute__((ext_vector_type(4))) float floatx4;

#define INV_SQRT2F 0.70710678118654752440f

// fragment-ordered bf16 weights (8.5 MB), filled by k_cvt each call
__device__ ushort g_wbuf[4259840];

__device__ __forceinline__ ushort f2bf(float f) {
    union { float f; uint32_t u; } c; c.f = f;
    uint32_t x = c.u;
    return (ushort)((x + 0x7fffu + ((x >> 16) & 1u)) >> 16);  // RTNE
}
__device__ __forceinline__ float softplus100(float x) {
    float z = 100.f * x;
    return fmaxf(x, 0.f) + __logf(1.f + __expf(-fabsf(z))) * 0.01f;
}
__device__ __forceinline__ int swz(int row, int col) {
    return (((col >> 3) ^ (row & 7)) << 3) | (col & 7);
}

// ---------------- weight cvt + fragment reorder ----------------
// dest per cluster: short8 i8 = (t*K32 + kc)*64 + lane; elem j:
// n = t*16 + (lane&15), k = kc*32 + (lane>>4)*8 + j. Zeros at edges.
struct Seg { const float* s; int off, nout, kw, k32, ttot, nclust; };
struct CvtAll { Seg seg[16]; };

__global__ void k_cvt(CvtAll c) {
    Seg sg = c.seg[blockIdx.y];
    ushort* d = g_wbuf + sg.off;
    const int pcs8 = sg.ttot * sg.k32 * 64;
    const int tot8 = pcs8 * sg.nclust;
    for (int i8 = blockIdx.x * blockDim.x + threadIdx.x; i8 < tot8;
         i8 += gridDim.x * blockDim.x) {
        int cl = i8 / pcs8;
        int r = i8 - cl * pcs8;
        int t = r / (sg.k32 * 64);
        int r2 = r - t * (sg.k32 * 64);
        int kc = r2 >> 6;
        int lane = r2 & 63;
        int n = t * 16 + (lane & 15);
        int kb = kc * 32 + (lane >> 4) * 8;
        const float* src = sg.s + (size_t)cl * sg.nout * sg.kw;
        short8 v = {0, 0, 0, 0, 0, 0, 0, 0};
        if (n < sg.nout) {
#pragma unroll
            for (int j = 0; j < 8; ++j) {
                int k = kb + j;
                if (k < sg.kw) v[j] = (short)f2bf(src[n * sg.kw + k]);
            }
        }
        *(short8*)(d + (size_t)i8 * 8) = v;
    }
}

// ---------------- embedding: 128 rows, cols 0..63 (zeros beyond 38) ----------------
template<int STRIDE>
__device__ void embed128(short* act, const float* pts, int row0, short* inp_sv) {
    for (int idx = threadIdx.x; idx < 128 * 64; idx += 1024) {
        int row = idx >> 6, col = idx & 63;
        float v = 0.f;
        if (col < 39) {
            int comp = (col < 3) ? col : (col - 3) % 3;
            float x = pts[(row0 + row) * 3 + comp];
            if (col < 3) v = x;
            else {
                int b = col - 3; int fi = b / 6; int r = b % 6;
                float a = x * (float)(1 << fi);
                v = (r < 3) ? __sinf(a) : __cosf(a);
            }
        }
        act[row * STRIDE + swz(row, col)] = (short)f2bf(v);
        if (inp_sv && col < 39) inp_sv[row * 40 + col] = (short)f2bf(v * INV_SQRT2F);
    }
}

// ---------------- one linear layer: 128 rows in LDS, 16 waves ----------------
// wave handles t-tiles {wave, wave+16} x 8 m-tiles; acc = 2x8 floatx4 (64 AGPR)
// (R5 structure: measured best — weights read once per CU, one barrier group)
template<int ACT, int STRIDE, int K>
__device__ void layer_mm(short* act, const ushort* __restrict__ Wf,
                         const float* __restrict__ bias, int Nout, float scale,
                         bool toLds, float* gOut, int gCol0, int gRow0)
{
    constexpr int K32 = K / 32;
    const int tid = threadIdx.x;
    const int wave = tid >> 6, lane = tid & 63;
    const int q = lane >> 4, li = lane & 15;
    const int Ttot = (Nout + 15) >> 4;

    floatx4 acc[2][8];
#pragma unroll
    for (int i = 0; i < 2; ++i)
#pragma unroll
        for (int m = 0; m < 8; ++m) acc[i][m] = (floatx4){0.f, 0.f, 0.f, 0.f};

    bool tv[2]; int nn[2]; const ushort* wb[2];
#pragma unroll
    for (int i = 0; i < 2; ++i) {
        int t = wave + 16 * i;
        tv[i] = t < Ttot;
        nn[i] = t * 16 + li;
        wb[i] = Wf + (size_t)t * K32 * 512 + lane * 8;
    }

    auto loadB = [&](int kc, short8* b) {
#pragma unroll
        for (int i = 0; i < 2; ++i) {
            short8 z = {0, 0, 0, 0, 0, 0, 0, 0};
            b[i] = tv[i] ? *(const short8*)(wb[i] + kc * 512) : z;
        }
    };
    auto step = [&](int kc, short8* b) {
        const int gq = kc * 4 + q;
#pragma unroll
        for (int h = 0; h < 2; ++h) {           // split m into halves: caps VGPR liveness
            short8 afr[4];
#pragma unroll
            for (int m2 = 0; m2 < 4; ++m2) {
                int row = (h * 4 + m2) * 16 + li;
                afr[m2] = *(const short8*)&act[row * STRIDE + ((gq ^ (row & 7)) << 3)];
            }
#pragma unroll
            for (int i = 0; i < 2; ++i) {
                if (!tv[i]) continue;
#pragma unroll
                for (int m2 = 0; m2 < 4; ++m2)
                    acc[i][h * 4 + m2] = __builtin_amdgcn_mfma_f32_16x16x32_bf16(
                        afr[m2], b[i], acc[i][h * 4 + m2], 0, 0, 0);
            }
        }
    };

    short8 b0[2], b1[2];
    loadB(0, b0);
#pragma unroll
    for (int kc = 0; kc < K32; kc += 2) {
        if (kc + 1 < K32) loadB(kc + 1, b1);
        step(kc, b0);
        if (kc + 2 < K32) loadB(kc + 2, b0);
        if (kc + 1 < K32) step(kc + 1, b1);
    }
    __syncthreads();  // act reads done before epilogue overwrites
#pragma unroll
    for (int i = 0; i < 2; ++i) {
        if (!tv[i]) continue;
        int n = nn[i];
        if (n < Nout) {
            float bs = bias[n];
#pragma unroll
            for (int m = 0; m < 8; ++m) {
                int rbase = m * 16 + q * 4;
#pragma unroll
                for (int r = 0; r < 4; ++r) {
                    float v = acc[i][m][r] + bs;
                    if (ACT == 1) v = softplus100(v);
                    else if (ACT == 2) v = fmaxf(v, 0.f);
                    else if (ACT == 3) v = tanhf(v);
                    v *= scale;
                    if (toLds) act[(rbase + r) * STRIDE + swz(rbase + r, n)] = (short)f2bf(v);
                    else gOut[(size_t)(gRow0 + rbase + r) * 263 + gCol0 + n] = v;
                }
            }
        }
    }
}

// ---------------- implicit network: 256 blocks x 1024 (one generation) ----------------
struct IP { int iw[9]; const float* ib[9]; };

__global__ __launch_bounds__(1024, 4) void k_impl(const float* __restrict__ pts,
                                                  IP p, float* __restrict__ out) {
    __shared__ short act[128 * 512];
    __shared__ short inp_sv[128 * 40];
    const int row0 = blockIdx.x * 128;
    embed128<512>(act, pts, row0, inp_sv);
    __syncthreads();
    layer_mm<1, 512, 64>(act, g_wbuf + p.iw[0], p.ib[0], 512, 1.f, true, nullptr, 0, 0);
    __syncthreads();
    layer_mm<1, 512, 512>(act, g_wbuf + p.iw[1], p.ib[1], 512, 1.f, true, nullptr, 0, 0);
    __syncthreads();
    layer_mm<1, 512, 512>(act, g_wbuf + p.iw[2], p.ib[2], 512, 1.f, true, nullptr, 0, 0);
    __syncthreads();
    // layer 3: softplus, then pre-scale by 1/sqrt(2) (skip-concat scale)
    layer_mm<1, 512, 512>(act, g_wbuf + p.iw[3], p.ib[3], 473, INV_SQRT2F, true, nullptr, 0, 0);
    for (int idx = threadIdx.x; idx < 128 * 64; idx += 1024) {
        int row = idx >> 6, col = idx & 63;
        if (col < 39) act[row * 512 + swz(row, 473 + col)] = inp_sv[row * 40 + col];
    }
    __syncthreads();
    layer_mm<1, 512, 512>(act, g_wbuf + p.iw[4], p.ib[4], 512, 1.f, true, nullptr, 0, 0);
    __syncthreads();
    layer_mm<1, 512, 512>(act, g_wbuf + p.iw[5], p.ib[5], 512, 1.f, true, nullptr, 0, 0);
    __syncthreads();
    layer_mm<1, 512, 512>(act, g_wbuf + p.iw[6], p.ib[6], 512, 1.f, true, nullptr, 0, 0);
    __syncthreads();
    layer_mm<1, 512, 512>(act, g_wbuf + p.iw[7], p.ib[7], 512, 1.f, true, nullptr, 0, 0);
    __syncthreads();
    layer_mm<0, 512, 512>(act, g_wbuf + p.iw[8], p.ib[8], 257, 1.f, false, out, 0, row0);
}

// ---------------- fused displacement + multi: 256 blocks (one generation) ----------------
// Each block: mult network first (act used 128-stride), then disp network.
struct DMP { int dw[4]; const float* db[4]; int mw[3]; const float* mb[3]; };

__global__ __launch_bounds__(1024, 4) void k_dm(const float* __restrict__ pts,
                                                DMP p, float* __restrict__ out,
                                                int rpc) {
    __shared__ short act[128 * 512];
    const int row0 = blockIdx.x * 128;
    // ---- multi displacement (tiny): cluster c covers this whole 128-row block ----
    const int c = row0 / rpc;
    // per-cluster fragment sizes: L0 8*2*512=8192, L1 8*4*512=16384, L2 1*4*512=2048
    const ushort* w0 = g_wbuf + p.mw[0] + c * 8192;
    const ushort* w1 = g_wbuf + p.mw[1] + c * 16384;
    const ushort* w2 = g_wbuf + p.mw[2] + c * 2048;
    embed128<128>(act, pts, row0, nullptr);
    __syncthreads();
    layer_mm<2, 128, 64>(act, w0, p.mb[0] + c * 128, 128, 1.f, true, nullptr, 0, 0);
    __syncthreads();
    layer_mm<2, 128, 128>(act, w1, p.mb[1] + c * 128, 128, 1.f, true, nullptr, 0, 0);
    __syncthreads();
    layer_mm<3, 128, 128>(act, w2, p.mb[2] + c * 3, 3, 1.f, false, out, 260, row0);
    __syncthreads();
    // ---- displacement network ----
    embed128<512>(act, pts, row0, nullptr);
    __syncthreads();
    layer_mm<2, 512, 64>(act, g_wbuf + p.dw[0], p.db[0], 512, 1.f, true, nullptr, 0, 0);
    __syncthreads();
    layer_mm<2, 512, 512>(act, g_wbuf + p.dw[1], p.db[1], 512, 1.f, true, nullptr, 0, 0);
    __syncthreads();
    layer_mm<2, 512, 512>(act, g_wbuf + p.dw[2], p.db[2], 512, 1.f, true, nullptr, 0, 0);
    __syncthreads();
    layer_mm<3, 512, 512>(act, g_wbuf + p.dw[3], p.db[3], 3, 1.f, false, out, 257, row0);
}

extern "C" void kernel_launch(void* const* d_in, const int* in_sizes, int n_in,
                              void* d_out, int out_size, void* d_ws, size_t ws_size,
                              hipStream_t stream) {
    const float* pts = (const float*)d_in[0];
    float* out = (float*)d_out;
    const int N = in_sizes[0] / 3;       // 32768
    const int nbI = N / 128;             // 256
    const int nbDM = N / 128;            // 256 (fused disp+mult)
    const int rpc = N / 64;              // rows per cluster (512)

    const int iN[9] = {512, 512, 512, 473, 512, 512, 512, 512, 257};
    const int iK[9] = {39, 512, 512, 512, 512, 512, 512, 512, 512};
    const int dN[4] = {512, 512, 512, 3};
    const int dK[4] = {39, 512, 512, 512};
    const int mN[3] = {128, 128, 3};
    const int mK[3] = {39, 128, 128};

    CvtAll cv; IP ip; DMP dm;
    int off = 0, seg = 0;
    auto add_seg = [&](const float* src, int nout, int kw, int nclust) -> int {
        int k32 = ((kw + 31) & ~31) / 32;
        int ttot = (nout + 15) >> 4;
        cv.seg[seg].s = src; cv.seg[seg].off = off;
        cv.seg[seg].nout = nout; cv.seg[seg].kw = kw;
        cv.seg[seg].k32 = k32; cv.seg[seg].ttot = ttot; cv.seg[seg].nclust = nclust;
        int my = off;
        off += ttot * k32 * 512 * nclust;
        ++seg;
        return my;
    };
    for (int l = 0; l < 9; ++l) {
        ip.iw[l] = add_seg((const float*)d_in[1 + 2 * l], iN[l], iK[l], 1);
        ip.ib[l] = (const float*)d_in[2 + 2 * l];
    }
    for (int l = 0; l < 4; ++l) {
        dm.dw[l] = add_seg((const float*)d_in[19 + 2 * l], dN[l], dK[l], 1);
        dm.db[l] = (const float*)d_in[20 + 2 * l];
    }
    for (int l = 0; l < 3; ++l) {
        dm.mw[l] = add_seg((const float*)d_in[27 + 2 * l], mN[l], mK[l], 64);
        dm.mb[l] = (const float*)d_in[28 + 2 * l];
    }

    k_cvt<<<dim3(256, 16), 256, 0, stream>>>(cv);
    k_impl<<<nbI, 1024, 0, stream>>>(pts, ip, out);
    k_dm<<<nbDM, 1024, 0, stream>>>(pts, dm, out, rpc);
}

// Round 10
// 418.017 us; speedup vs baseline: 2.2661x; 1.1119x over previous
//
#include <hip/hip_runtime.h>
#include <hip/hip_bf16.h>
#include <stdint.h>

typedef __attribute__((ext_vector_type(8))) short short8;
typedef __attribute__((ext_vector_type(4))) float floatx4;
typedef __attribute__((ext_vector_type(2))) uint uint2v;

#define INV_SQRT2F 0.70710678118654752440f

// fragment-ordered bf16 weights (8.5 MB), filled by k_cvt each call
__device__ ushort g_wbuf[4259840];

__device__ __forceinline__ ushort f2bf(float f) {
    union { float f; uint32_t u; } c; c.f = f;
    uint32_t x = c.u;
    return (ushort)((x + 0x7fffu + ((x >> 16) & 1u)) >> 16);  // RTNE
}
__device__ __forceinline__ uint pk2bf(float a, float b) {   // v_cvt_pk_bf16_f32
    union { __hip_bfloat162 h; uint u; } c;
    c.h = __float22bfloat162_rn(make_float2(a, b));
    return c.u;
}
__device__ __forceinline__ float softplus100(float x) {
    float z = 100.f * x;
    return fmaxf(x, 0.f) + __logf(1.f + __expf(-fabsf(z))) * 0.01f;
}
__device__ __forceinline__ int swz(int row, int col) {
    return (((col >> 3) ^ (row & 7)) << 3) | (col & 7);
}

// ---------------- weight cvt + fragment reorder ----------------
// dest per cluster: short8 i8 = (t*K32 + kc)*64 + lane; elem j:
// n = t*16 + (lane&15), k = kc*32 + (lane>>4)*8 + j. Zeros at edges.
// (A and B operand layouts are identical for mfma 16x16x32, so this serves
// as the A-operand (weights-first) layout too.)
struct Seg { const float* s; int off, nout, kw, k32, ttot, nclust; };
struct CvtAll { Seg seg[16]; };

__global__ void k_cvt(CvtAll c) {
    Seg sg = c.seg[blockIdx.y];
    ushort* d = g_wbuf + sg.off;
    const int pcs8 = sg.ttot * sg.k32 * 64;
    const int tot8 = pcs8 * sg.nclust;
    for (int i8 = blockIdx.x * blockDim.x + threadIdx.x; i8 < tot8;
         i8 += gridDim.x * blockDim.x) {
        int cl = i8 / pcs8;
        int r = i8 - cl * pcs8;
        int t = r / (sg.k32 * 64);
        int r2 = r - t * (sg.k32 * 64);
        int kc = r2 >> 6;
        int lane = r2 & 63;
        int n = t * 16 + (lane & 15);
        int kb = kc * 32 + (lane >> 4) * 8;
        const float* src = sg.s + (size_t)cl * sg.nout * sg.kw;
        short8 v = {0, 0, 0, 0, 0, 0, 0, 0};
        if (n < sg.nout) {
#pragma unroll
            for (int j = 0; j < 8; ++j) {
                int k = kb + j;
                if (k < sg.kw) v[j] = (short)f2bf(src[n * sg.kw + k]);
            }
        }
        *(short8*)(d + (size_t)i8 * 8) = v;
    }
}

// ---------------- embedding: 128 rows, cols 0..63 (zeros beyond 38) ----------------
template<int STRIDE>
__device__ void embed128(short* act, const float* pts, int row0, short* inp_sv) {
    for (int idx = threadIdx.x; idx < 128 * 64; idx += 1024) {
        int row = idx >> 6, col = idx & 63;
        float v = 0.f;
        if (col < 39) {
            int comp = (col < 3) ? col : (col - 3) % 3;
            float x = pts[(row0 + row) * 3 + comp];
            if (col < 3) v = x;
            else {
                int b = col - 3; int fi = b / 6; int r = b % 6;
                float a = x * (float)(1 << fi);
                v = (r < 3) ? __sinf(a) : __cosf(a);
            }
        }
        act[row * STRIDE + swz(row, col)] = (short)f2bf(v);
        if (inp_sv && col < 39) inp_sv[row * 40 + col] = (short)f2bf(v * INV_SQRT2F);
    }
}

// ---------------- one linear layer: 128 rows in LDS, 16 waves ----------------
// R9 geometry (measured best): wave handles t-tiles {wave, wave+16} x 8 m-tiles.
// Swapped operands: mfma(W, act) -> D rows = out-channel n, cols = act row ->
// each lane holds 4 consecutive n for one act row -> packed b64 LDS writes.
template<int ACT, int STRIDE, int K>
__device__ void layer_mm(short* act, const ushort* __restrict__ Wf,
                         const float* __restrict__ bias, int Nout, float scale,
                         bool toLds, float* gOut, int gCol0, int gRow0)
{
    constexpr int K32 = K / 32;
    const int tid = threadIdx.x;
    const int wave = tid >> 6, lane = tid & 63;
    const int q = lane >> 4, li = lane & 15;
    const int Ttot = (Nout + 15) >> 4;

    floatx4 acc[2][8];
#pragma unroll
    for (int i = 0; i < 2; ++i)
#pragma unroll
        for (int m = 0; m < 8; ++m) acc[i][m] = (floatx4){0.f, 0.f, 0.f, 0.f};

    bool tv[2]; const ushort* wb[2];
#pragma unroll
    for (int i = 0; i < 2; ++i) {
        int t = wave + 16 * i;
        tv[i] = t < Ttot;
        wb[i] = Wf + (size_t)t * K32 * 512 + lane * 8;
    }

    if (tv[0]) {   // waves with no valid t-tile skip the whole K-loop
        auto loadB = [&](int kc, short8* b) {
#pragma unroll
            for (int i = 0; i < 2; ++i)
                if (tv[i]) b[i] = *(const short8*)(wb[i] + kc * 512);
        };
        auto step = [&](int kc, short8* b) {
            const int gq = kc * 4 + q;
#pragma unroll
            for (int h = 0; h < 2; ++h) {       // split m into halves: caps VGPR liveness
                short8 afr[4];
#pragma unroll
                for (int m2 = 0; m2 < 4; ++m2) {
                    int row = (h * 4 + m2) * 16 + li;
                    afr[m2] = *(const short8*)&act[row * STRIDE + ((gq ^ (row & 7)) << 3)];
                }
#pragma unroll
                for (int i = 0; i < 2; ++i) {
                    if (!tv[i]) continue;
#pragma unroll
                    for (int m2 = 0; m2 < 4; ++m2)
                        acc[i][h * 4 + m2] = __builtin_amdgcn_mfma_f32_16x16x32_bf16(
                            b[i], afr[m2], acc[i][h * 4 + m2], 0, 0, 0);
                }
            }
        };

        short8 b0[2], b1[2];
        loadB(0, b0);
#pragma unroll
        for (int kc = 0; kc < K32; kc += 2) {
            if (kc + 1 < K32) loadB(kc + 1, b1);
            step(kc, b0);
            if (kc + 2 < K32) loadB(kc + 2, b0);
            if (kc + 1 < K32) step(kc + 1, b1);
        }
    }
    __syncthreads();  // act reads done before epilogue overwrites
#pragma unroll
    for (int i = 0; i < 2; ++i) {
        if (!tv[i]) continue;
        const int nb = (wave + 16 * i) * 16 + q * 4;
        if (nb >= Nout) continue;
        const bool fullN = (nb + 4) <= Nout;
        float bs[4];
        if (fullN) {
            float4 b4 = *(const float4*)(bias + nb);
            bs[0] = b4.x; bs[1] = b4.y; bs[2] = b4.z; bs[3] = b4.w;
        } else {
#pragma unroll
            for (int r = 0; r < 4; ++r) bs[r] = (nb + r < Nout) ? bias[nb + r] : 0.f;
        }
#pragma unroll
        for (int m = 0; m < 8; ++m) {
            const int row = m * 16 + li;
            float v[4];
#pragma unroll
            for (int r = 0; r < 4; ++r) {
                float x = acc[i][m][r] + bs[r];
                if (ACT == 1) x = softplus100(x);
                else if (ACT == 2) x = fmaxf(x, 0.f);
                else if (ACT == 3) x = tanhf(x);
                v[r] = x * scale;
            }
            if (toLds) {
                if (fullN) {
                    int g = (nb >> 3) ^ (row & 7);
                    uint2v pk = {pk2bf(v[0], v[1]), pk2bf(v[2], v[3])};
                    *(uint2v*)&act[row * STRIDE + (g << 3) + (nb & 7)] = pk;
                } else {
#pragma unroll
                    for (int r = 0; r < 4; ++r)
                        if (nb + r < Nout)
                            act[row * STRIDE + swz(row, nb + r)] = (short)f2bf(v[r]);
                }
            } else {
#pragma unroll
                for (int r = 0; r < 4; ++r)
                    if (nb + r < Nout)
                        gOut[(size_t)(gRow0 + row) * 263 + gCol0 + nb + r] = v[r];
            }
        }
    }
}

// ---------------- implicit network: 256 blocks x 1024 (one generation) ----------------
struct IP { int iw[9]; const float* ib[9]; };

__global__ __launch_bounds__(1024, 4) void k_impl(const float* __restrict__ pts,
                                                  IP p, float* __restrict__ out) {
    __shared__ __align__(16) short act[128 * 512];
    __shared__ short inp_sv[128 * 40];
    const int row0 = blockIdx.x * 128;
    embed128<512>(act, pts, row0, inp_sv);
    __syncthreads();
    layer_mm<1, 512, 64>(act, g_wbuf + p.iw[0], p.ib[0], 512, 1.f, true, nullptr, 0, 0);
    __syncthreads();
    layer_mm<1, 512, 512>(act, g_wbuf + p.iw[1], p.ib[1], 512, 1.f, true, nullptr, 0, 0);
    __syncthreads();
    layer_mm<1, 512, 512>(act, g_wbuf + p.iw[2], p.ib[2], 512, 1.f, true, nullptr, 0, 0);
    __syncthreads();
    // layer 3: softplus, then pre-scale by 1/sqrt(2) (skip-concat scale)
    layer_mm<1, 512, 512>(act, g_wbuf + p.iw[3], p.ib[3], 473, INV_SQRT2F, true, nullptr, 0, 0);
    for (int idx = threadIdx.x; idx < 128 * 64; idx += 1024) {
        int row = idx >> 6, col = idx & 63;
        if (col < 39) act[row * 512 + swz(row, 473 + col)] = inp_sv[row * 40 + col];
    }
    __syncthreads();
    layer_mm<1, 512, 512>(act, g_wbuf + p.iw[4], p.ib[4], 512, 1.f, true, nullptr, 0, 0);
    __syncthreads();
    layer_mm<1, 512, 512>(act, g_wbuf + p.iw[5], p.ib[5], 512, 1.f, true, nullptr, 0, 0);
    __syncthreads();
    layer_mm<1, 512, 512>(act, g_wbuf + p.iw[6], p.ib[6], 512, 1.f, true, nullptr, 0, 0);
    __syncthreads();
    layer_mm<1, 512, 512>(act, g_wbuf + p.iw[7], p.ib[7], 512, 1.f, true, nullptr, 0, 0);
    __syncthreads();
    layer_mm<0, 512, 512>(act, g_wbuf + p.iw[8], p.ib[8], 257, 1.f, false, out, 0, row0);
}

// ---------------- fused displacement + multi: 256 blocks (one generation) ----------------
struct DMP { int dw[4]; const float* db[4]; int mw[3]; const float* mb[3]; };

__global__ __launch_bounds__(1024, 4) void k_dm(const float* __restrict__ pts,
                                                DMP p, float* __restrict__ out,
                                                int rpc) {
    __shared__ __align__(16) short act[128 * 512];
    const int row0 = blockIdx.x * 128;
    // ---- multi displacement (tiny): cluster c covers this whole 128-row block ----
    const int c = row0 / rpc;
    // per-cluster fragment sizes: L0 8*2*512=8192, L1 8*4*512=16384, L2 1*4*512=2048
    const ushort* w0 = g_wbuf + p.mw[0] + c * 8192;
    const ushort* w1 = g_wbuf + p.mw[1] + c * 16384;
    const ushort* w2 = g_wbuf + p.mw[2] + c * 2048;
    embed128<128>(act, pts, row0, nullptr);
    __syncthreads();
    layer_mm<2, 128, 64>(act, w0, p.mb[0] + c * 128, 128, 1.f, true, nullptr, 0, 0);
    __syncthreads();
    layer_mm<2, 128, 128>(act, w1, p.mb[1] + c * 128, 128, 1.f, true, nullptr, 0, 0);
    __syncthreads();
    layer_mm<3, 128, 128>(act, w2, p.mb[2] + c * 3, 3, 1.f, false, out, 260, row0);
    __syncthreads();
    // ---- displacement network ----
    embed128<512>(act, pts, row0, nullptr);
    __syncthreads();
    layer_mm<2, 512, 64>(act, g_wbuf + p.dw[0], p.db[0], 512, 1.f, true, nullptr, 0, 0);
    __syncthreads();
    layer_mm<2, 512, 512>(act, g_wbuf + p.dw[1], p.db[1], 512, 1.f, true, nullptr, 0, 0);
    __syncthreads();
    layer_mm<2, 512, 512>(act, g_wbuf + p.dw[2], p.db[2], 512, 1.f, true, nullptr, 0, 0);
    __syncthreads();
    layer_mm<3, 512, 512>(act, g_wbuf + p.dw[3], p.db[3], 3, 1.f, false, out, 257, row0);
}

extern "C" void kernel_launch(void* const* d_in, const int* in_sizes, int n_in,
                              void* d_out, int out_size, void* d_ws, size_t ws_size,
                              hipStream_t stream) {
    const float* pts = (const float*)d_in[0];
    float* out = (float*)d_out;
    const int N = in_sizes[0] / 3;       // 32768
    const int nbI = N / 128;             // 256
    const int nbDM = N / 128;            // 256 (fused disp+mult)
    const int rpc = N / 64;              // rows per cluster (512)

    const int iN[9] = {512, 512, 512, 473, 512, 512, 512, 512, 257};
    const int iK[9] = {39, 512, 512, 512, 512, 512, 512, 512, 512};
    const int dN[4] = {512, 512, 512, 3};
    const int dK[4] = {39, 512, 512, 512};
    const int mN[3] = {128, 128, 3};
    const int mK[3] = {39, 128, 128};

    CvtAll cv; IP ip; DMP dm;
    int off = 0, seg = 0;
    auto add_seg = [&](const float* src, int nout, int kw, int nclust) -> int {
        int k32 = ((kw + 31) & ~31) / 32;
        int ttot = (nout + 15) >> 4;
        cv.seg[seg].s = src; cv.seg[seg].off = off;
        cv.seg[seg].nout = nout; cv.seg[seg].kw = kw;
        cv.seg[seg].k32 = k32; cv.seg[seg].ttot = ttot; cv.seg[seg].nclust = nclust;
        int my = off;
        off += ttot * k32 * 512 * nclust;
        ++seg;
        return my;
    };
    for (int l = 0; l < 9; ++l) {
        ip.iw[l] = add_seg((const float*)d_in[1 + 2 * l], iN[l], iK[l], 1);
        ip.ib[l] = (const float*)d_in[2 + 2 * l];
    }
    for (int l = 0; l < 4; ++l) {
        dm.dw[l] = add_seg((const float*)d_in[19 + 2 * l], dN[l], dK[l], 1);
        dm.db[l] = (const float*)d_in[20 + 2 * l];
    }
    for (int l = 0; l < 3; ++l) {
        dm.mw[l] = add_seg((const float*)d_in[27 + 2 * l], mN[l], mK[l], 64);
        dm.mb[l] = (const float*)d_in[28 + 2 * l];
    }

    k_cvt<<<dim3(256, 16), 256, 0, stream>>>(cv);
    k_impl<<<nbI, 1024, 0, stream>>>(pts, ip, out);
    k_dm<<<nbDM, 1024, 0, stream>>>(pts, dm, out, rpc);
}

// Round 11
// 405.173 us; speedup vs baseline: 2.3379x; 1.0317x over previous
//
#include <hip/hip_runtime.h>
#include <hip/hip_bf16.h>
#include <stdint.h>

typedef __attribute__((ext_vector_type(8))) short short8;
typedef __attribute__((ext_vector_type(4))) float floatx4;
typedef __attribute__((ext_vector_type(2))) uint uint2v;

#define INV_SQRT2F 0.70710678118654752440f

// fragment-ordered bf16 weights (8.5 MB), filled by k_cvt each call
__device__ ushort g_wbuf[4259840];

__device__ __forceinline__ ushort f2bf(float f) {
    union { float f; uint32_t u; } c; c.f = f;
    uint32_t x = c.u;
    return (ushort)((x + 0x7fffu + ((x >> 16) & 1u)) >> 16);  // RTNE
}
__device__ __forceinline__ uint pk2bf(float a, float b) {   // v_cvt_pk_bf16_f32
    union { __hip_bfloat162 h; uint u; } c;
    c.h = __float22bfloat162_rn(make_float2(a, b));
    return c.u;
}
__device__ __forceinline__ float softplus100(float x) {
    float z = 100.f * x;
    return fmaxf(x, 0.f) + __logf(1.f + __expf(-fabsf(z))) * 0.01f;
}
// fragment-major index (in shorts) of (row, ch) for a layout with K32 kc-groups:
// matches the MFMA operand layout: elem j of lane (q*16+li) at (m,kc) is
// row = m*16+li, ch = kc*32 + q*8 + j.
__device__ __forceinline__ int fidx(int K32, int row, int ch) {
    return (((row >> 4) * K32 + (ch >> 5)) * 64 + ((ch >> 3) & 3) * 16 + (row & 15)) * 8 + (ch & 7);
}

// ---------------- weight cvt + fragment reorder ----------------
// dest per cluster: short8 i8 = (t*K32 + kc)*64 + lane; elem j:
// n = t*16 + (lane&15), k = kc*32 + (lane>>4)*8 + j. Zeros at edges.
struct Seg { const float* s; int off, nout, kw, k32, ttot, nclust; };
struct CvtAll { Seg seg[16]; };

__global__ void k_cvt(CvtAll c) {
    Seg sg = c.seg[blockIdx.y];
    ushort* d = g_wbuf + sg.off;
    const int pcs8 = sg.ttot * sg.k32 * 64;
    const int tot8 = pcs8 * sg.nclust;
    for (int i8 = blockIdx.x * blockDim.x + threadIdx.x; i8 < tot8;
         i8 += gridDim.x * blockDim.x) {
        int cl = i8 / pcs8;
        int r = i8 - cl * pcs8;
        int t = r / (sg.k32 * 64);
        int r2 = r - t * (sg.k32 * 64);
        int kc = r2 >> 6;
        int lane = r2 & 63;
        int n = t * 16 + (lane & 15);
        int kb = kc * 32 + (lane >> 4) * 8;
        const float* src = sg.s + (size_t)cl * sg.nout * sg.kw;
        short8 v = {0, 0, 0, 0, 0, 0, 0, 0};
        if (n < sg.nout) {
#pragma unroll
            for (int j = 0; j < 8; ++j) {
                int k = kb + j;
                if (k < sg.kw) v[j] = (short)f2bf(src[n * sg.kw + k]);
            }
        }
        *(short8*)(d + (size_t)i8 * 8) = v;
    }
}

// ---------------- embedding: 128 rows, cols 0..63 (zeros beyond 38) ----------------
template<int K32OUT>
__device__ void embed128(short* act, const float* pts, int row0, short* inp_sv) {
    for (int idx = threadIdx.x; idx < 128 * 64; idx += 1024) {
        int row = idx >> 6, col = idx & 63;
        float v = 0.f;
        if (col < 39) {
            int comp = (col < 3) ? col : (col - 3) % 3;
            float x = pts[(row0 + row) * 3 + comp];
            if (col < 3) v = x;
            else {
                int b = col - 3; int fi = b / 6; int r = b % 6;
                float a = x * (float)(1 << fi);
                v = (r < 3) ? __sinf(a) : __cosf(a);
            }
        }
        act[fidx(K32OUT, row, col)] = (short)f2bf(v);
        if (inp_sv && col < 39) inp_sv[row * 40 + col] = (short)f2bf(v * INV_SQRT2F);
    }
}

// ---------------- one linear layer: 128 rows in LDS (fragment-major), 16 waves ----
// R9 geometry: wave handles t-tiles {wave, wave+16} x 8 m-tiles.
// Swapped operands: mfma(W, act) -> each lane holds 4 consecutive n for one row.
// Reads are contiguous b128 (zero conflicts, immediate offsets); epilogue writes
// land directly in the NEXT layer's fragment positions (K32OUT layout).
template<int ACT, int K32IN, int K32OUT>
__device__ void layer_mm(short* act, const ushort* __restrict__ Wf,
                         const float* __restrict__ bias, int Nout, float scale,
                         bool toLds, float* gOut, int gCol0, int gRow0)
{
    const int tid = threadIdx.x;
    const int wave = tid >> 6, lane = tid & 63;
    const int q = lane >> 4, li = lane & 15;
    const int lane8 = lane * 8;
    const int Ttot = (Nout + 15) >> 4;

    floatx4 acc[2][8];
#pragma unroll
    for (int i = 0; i < 2; ++i)
#pragma unroll
        for (int m = 0; m < 8; ++m) acc[i][m] = (floatx4){0.f, 0.f, 0.f, 0.f};

    bool tv[2]; const ushort* wb[2];
#pragma unroll
    for (int i = 0; i < 2; ++i) {
        int t = wave + 16 * i;
        tv[i] = t < Ttot;
        wb[i] = Wf + (size_t)t * K32IN * 512 + lane8;
    }

    if (tv[0]) {   // waves with no valid t-tile skip the whole K-loop
        auto loadB = [&](int kc, short8* b) {
#pragma unroll
            for (int i = 0; i < 2; ++i)
                if (tv[i]) b[i] = *(const short8*)(wb[i] + kc * 512);
        };
        auto step = [&](int kc, short8* b) {
#pragma unroll
            for (int h = 0; h < 2; ++h) {       // split m into halves: caps VGPR liveness
                short8 afr[4];
#pragma unroll
                for (int m2 = 0; m2 < 4; ++m2)
                    afr[m2] = *(const short8*)&act[((h * 4 + m2) * K32IN + kc) * 512 + lane8];
#pragma unroll
                for (int i = 0; i < 2; ++i) {
                    if (!tv[i]) continue;
#pragma unroll
                    for (int m2 = 0; m2 < 4; ++m2)
                        acc[i][h * 4 + m2] = __builtin_amdgcn_mfma_f32_16x16x32_bf16(
                            b[i], afr[m2], acc[i][h * 4 + m2], 0, 0, 0);
                }
            }
        };

        short8 b0[2], b1[2];
        loadB(0, b0);
#pragma unroll
        for (int kc = 0; kc < K32IN; kc += 2) {
            if (kc + 1 < K32IN) loadB(kc + 1, b1);
            step(kc, b0);
            if (kc + 2 < K32IN) loadB(kc + 2, b0);
            if (kc + 1 < K32IN) step(kc + 1, b1);
        }
    }
    __syncthreads();  // act reads done before epilogue overwrites
#pragma unroll
    for (int i = 0; i < 2; ++i) {
        if (!tv[i]) continue;
        const int nb = (wave + 16 * i) * 16 + q * 4;
        if (nb >= Nout) continue;
        const bool fullN = (nb + 4) <= Nout;
        float bs[4];
        if (fullN) {
            float4 b4 = *(const float4*)(bias + nb);
            bs[0] = b4.x; bs[1] = b4.y; bs[2] = b4.z; bs[3] = b4.w;
        } else {
#pragma unroll
            for (int r = 0; r < 4; ++r) bs[r] = (nb + r < Nout) ? bias[nb + r] : 0.f;
        }
        // next-layer fragment coords of this lane's 4 consecutive channels
        const int wbase = ((nb >> 5)) * 512 + ((nb >> 3) & 3) * 128 + li * 8 + (nb & 7);
#pragma unroll
        for (int m = 0; m < 8; ++m) {
            const int row = m * 16 + li;
            float v[4];
#pragma unroll
            for (int r = 0; r < 4; ++r) {
                float x = acc[i][m][r] + bs[r];
                if (ACT == 1) x = softplus100(x);
                else if (ACT == 2) x = fmaxf(x, 0.f);
                else if (ACT == 3) x = tanhf(x);
                v[r] = x * scale;
            }
            if (toLds) {
                if (fullN) {
                    uint2v pk = {pk2bf(v[0], v[1]), pk2bf(v[2], v[3])};
                    *(uint2v*)&act[m * K32OUT * 512 + wbase] = pk;
                } else {
#pragma unroll
                    for (int r = 0; r < 4; ++r)
                        if (nb + r < Nout)
                            act[fidx(K32OUT, row, nb + r)] = (short)f2bf(v[r]);
                }
            } else {
#pragma unroll
                for (int r = 0; r < 4; ++r)
                    if (nb + r < Nout)
                        gOut[(size_t)(gRow0 + row) * 263 + gCol0 + nb + r] = v[r];
            }
        }
    }
}

// ---------------- implicit network: 256 blocks x 1024 (one generation) ----------------
struct IP { int iw[9]; const float* ib[9]; };

__global__ __launch_bounds__(1024, 4) void k_impl(const float* __restrict__ pts,
                                                  IP p, float* __restrict__ out) {
    __shared__ __align__(16) short act[128 * 512];
    __shared__ short inp_sv[128 * 40];
    const int row0 = blockIdx.x * 128;
    embed128<2>(act, pts, row0, inp_sv);
    __syncthreads();
    layer_mm<1, 2, 16>(act, g_wbuf + p.iw[0], p.ib[0], 512, 1.f, true, nullptr, 0, 0);
    __syncthreads();
    layer_mm<1, 16, 16>(act, g_wbuf + p.iw[1], p.ib[1], 512, 1.f, true, nullptr, 0, 0);
    __syncthreads();
    layer_mm<1, 16, 16>(act, g_wbuf + p.iw[2], p.ib[2], 512, 1.f, true, nullptr, 0, 0);
    __syncthreads();
    // layer 3: softplus, then pre-scale by 1/sqrt(2) (skip-concat scale)
    layer_mm<1, 16, 16>(act, g_wbuf + p.iw[3], p.ib[3], 473, INV_SQRT2F, true, nullptr, 0, 0);
    for (int idx = threadIdx.x; idx < 128 * 64; idx += 1024) {
        int row = idx >> 6, col = idx & 63;
        if (col < 39) act[fidx(16, row, 473 + col)] = inp_sv[row * 40 + col];
    }
    __syncthreads();
    layer_mm<1, 16, 16>(act, g_wbuf + p.iw[4], p.ib[4], 512, 1.f, true, nullptr, 0, 0);
    __syncthreads();
    layer_mm<1, 16, 16>(act, g_wbuf + p.iw[5], p.ib[5], 512, 1.f, true, nullptr, 0, 0);
    __syncthreads();
    layer_mm<1, 16, 16>(act, g_wbuf + p.iw[6], p.ib[6], 512, 1.f, true, nullptr, 0, 0);
    __syncthreads();
    layer_mm<1, 16, 16>(act, g_wbuf + p.iw[7], p.ib[7], 512, 1.f, true, nullptr, 0, 0);
    __syncthreads();
    layer_mm<0, 16, 16>(act, g_wbuf + p.iw[8], p.ib[8], 257, 1.f, false, out, 0, row0);
}

// ---------------- fused displacement + multi: 256 blocks (one generation) ----------------
struct DMP { int dw[4]; const float* db[4]; int mw[3]; const float* mb[3]; };

__global__ __launch_bounds__(1024, 4) void k_dm(const float* __restrict__ pts,
                                                DMP p, float* __restrict__ out,
                                                int rpc) {
    __shared__ __align__(16) short act[128 * 512];
    const int row0 = blockIdx.x * 128;
    // ---- multi displacement (tiny): cluster c covers this whole 128-row block ----
    const int c = row0 / rpc;
    // per-cluster fragment sizes: L0 8*2*512=8192, L1 8*4*512=16384, L2 1*4*512=2048
    const ushort* w0 = g_wbuf + p.mw[0] + c * 8192;
    const ushort* w1 = g_wbuf + p.mw[1] + c * 16384;
    const ushort* w2 = g_wbuf + p.mw[2] + c * 2048;
    embed128<2>(act, pts, row0, nullptr);
    __syncthreads();
    layer_mm<2, 2, 4>(act, w0, p.mb[0] + c * 128, 128, 1.f, true, nullptr, 0, 0);
    __syncthreads();
    layer_mm<2, 4, 4>(act, w1, p.mb[1] + c * 128, 128, 1.f, true, nullptr, 0, 0);
    __syncthreads();
    layer_mm<3, 4, 4>(act, w2, p.mb[2] + c * 3, 3, 1.f, false, out, 260, row0);
    __syncthreads();
    // ---- displacement network ----
    embed128<2>(act, pts, row0, nullptr);
    __syncthreads();
    layer_mm<2, 2, 16>(act, g_wbuf + p.dw[0], p.db[0], 512, 1.f, true, nullptr, 0, 0);
    __syncthreads();
    layer_mm<2, 16, 16>(act, g_wbuf + p.dw[1], p.db[1], 512, 1.f, true, nullptr, 0, 0);
    __syncthreads();
    layer_mm<2, 16, 16>(act, g_wbuf + p.dw[2], p.db[2], 512, 1.f, true, nullptr, 0, 0);
    __syncthreads();
    layer_mm<3, 16, 16>(act, g_wbuf + p.dw[3], p.db[3], 3, 1.f, false, out, 257, row0);
}

extern "C" void kernel_launch(void* const* d_in, const int* in_sizes, int n_in,
                              void* d_out, int out_size, void* d_ws, size_t ws_size,
                              hipStream_t stream) {
    const float* pts = (const float*)d_in[0];
    float* out = (float*)d_out;
    const int N = in_sizes[0] / 3;       // 32768
    const int nbI = N / 128;             // 256
    const int nbDM = N / 128;            // 256 (fused disp+mult)
    const int rpc = N / 64;              // rows per cluster (512)

    const int iN[9] = {512, 512, 512, 473, 512, 512, 512, 512, 257};
    const int iK[9] = {39, 512, 512, 512, 512, 512, 512, 512, 512};
    const int dN[4] = {512, 512, 512, 3};
    const int dK[4] = {39, 512, 512, 512};
    const int mN[3] = {128, 128, 3};
    const int mK[3] = {39, 128, 128};

    CvtAll cv; IP ip; DMP dm;
    int off = 0, seg = 0;
    auto add_seg = [&](const float* src, int nout, int kw, int nclust) -> int {
        int k32 = ((kw + 31) & ~31) / 32;
        int ttot = (nout + 15) >> 4;
        cv.seg[seg].s = src; cv.seg[seg].off = off;
        cv.seg[seg].nout = nout; cv.seg[seg].kw = kw;
        cv.seg[seg].k32 = k32; cv.seg[seg].ttot = ttot; cv.seg[seg].nclust = nclust;
        int my = off;
        off += ttot * k32 * 512 * nclust;
        ++seg;
        return my;
    };
    for (int l = 0; l < 9; ++l) {
        ip.iw[l] = add_seg((const float*)d_in[1 + 2 * l], iN[l], iK[l], 1);
        ip.ib[l] = (const float*)d_in[2 + 2 * l];
    }
    for (int l = 0; l < 4; ++l) {
        dm.dw[l] = add_seg((const float*)d_in[19 + 2 * l], dN[l], dK[l], 1);
        dm.db[l] = (const float*)d_in[20 + 2 * l];
    }
    for (int l = 0; l < 3; ++l) {
        dm.mw[l] = add_seg((const float*)d_in[27 + 2 * l], mN[l], mK[l], 64);
        dm.mb[l] = (const float*)d_in[28 + 2 * l];
    }

    k_cvt<<<dim3(256, 16), 256, 0, stream>>>(cv);
    k_impl<<<nbI, 1024, 0, stream>>>(pts, ip, out);
    k_dm<<<nbDM, 1024, 0, stream>>>(pts, dm, out, rpc);
}